// Round 16
// baseline (3461.168 us; speedup 1.0000x reference)
//
#include <hip/hip_runtime.h>

#define TT 128
#define BB 64
#define HH 1024
#define LL 4
#define NWG 256

typedef _Float16 f16;
typedef __attribute__((ext_vector_type(4))) _Float16 f16x4;
typedef __attribute__((ext_vector_type(8))) _Float16 f16x8;
typedef __attribute__((ext_vector_type(4))) float f32x4;
typedef unsigned long long u64;

// ---------------- persistent device buffers ----------------
// Fragment layout for a [64 rows x 1024 k] fp16 tensor (HW-verified r1/r4/r6/r7):
//   flat = ((rg*32 + ktp)*64 + lane)*8 + e
//   rg = row>>4, ktp = k>>5, lane = ((k>>2)&3)<<4 | (row&15), e = ((k>>4)&1)<<2 | (k&3)
__device__ __align__(16) f16 g_in16[TT][65536];        // inputs, frag layout per t
// 8-deep rotating state slots (t&7): slot (t+1)&7 holds post-step-t state.
// Producers publish with device-scope atomic stores; consumers read with
// device-scope atomic loads (bypass stale L1/L2). NO cache-wide fences (r10/r15).
__device__ __align__(16) f16 g_c16[LL][8][65536];      // cell state (feeds next layer)
__device__ __align__(16) f16 g_h16[LL][8][65536];      // hidden state (U-matmul input)
__device__ __align__(16) float g_c32[LL][BB][HH];      // cell state master f32 (WG-private)
// per-producer epoch: g_ep[j][s] = t+1 after WG (j,s) finished step t (atomic STORE).
__device__ unsigned g_ep[LL][64];

// ---------------- init: zero h slot 0 + epochs + c32 ----------------
__global__ void k_init() {
  unsigned tid = blockIdx.x * blockDim.x + threadIdx.x;
  unsigned n = gridDim.x * blockDim.x;
  float* c32 = &g_c32[0][0][0];
  for (unsigned i = tid; i < LL * BB * HH; i += n) c32[i] = 0.f;
  for (unsigned i = tid; i < LL * 32768; i += n) {
    int jj = i >> 15, q = i & 32767;
    ((unsigned*)&g_h16[jj][0][0])[q] = 0u;   // h(0) = 0 in slot 0
  }
  unsigned* pe = &g_ep[0][0];
  for (unsigned i = tid; i < LL * 64; i += n) pe[i] = 0u;
}

// ---------------- pack inputs f32 -> fp16 fragment layout (verified) ----------------
__global__ void k_pack_in(const float* __restrict__ inp) {
  int tid = blockIdx.x * blockDim.x + threadIdx.x;
  int t = tid >> 14, q = tid & 16383;
  int row = q >> 8, hu = (q & 255) << 2;
  const float4 x = *(const float4*)(inp + ((size_t)t << 16) + (row << 10) + hu);
  int rg = row >> 4, ktp = hu >> 5;
  int ln = (((hu >> 2) & 3) << 4) | (row & 15);
  int e0 = ((hu >> 4) & 1) << 2;
  f16x4 v = {(f16)x.x, (f16)x.y, (f16)x.z, (f16)x.w};
  *(f16x4*)&g_in16[t][(((rg * 32 + ktp) * 64 + ln) << 3) + e0] = v;
}

// ---------------- helpers ----------------
__device__ __forceinline__ float sigf(float x) { return 1.f / (1.f + __expf(-x)); }
__device__ __forceinline__ float tanh_(float x) {
  float q = __expf(-2.f * fabsf(x));
  return copysignf((1.f - q) / (1.f + q), x);
}
__device__ __forceinline__ f16x4 lo8(f16x8 v) { return __builtin_shufflevector(v, v, 0, 1, 2, 3); }
__device__ __forceinline__ f16x4 hi8(f16x8 v) { return __builtin_shufflevector(v, v, 4, 5, 6, 7); }
// lane-parallel wait: lane l polls its own producer-epoch slot; exit when all >= target
__device__ __forceinline__ void waitep(const unsigned* ep, unsigned target) {
  for (;;) {
    unsigned e = __hip_atomic_load(ep, __ATOMIC_RELAXED, __HIP_MEMORY_SCOPE_AGENT);
    if (__all((int)(e >= target))) break;
    __builtin_amdgcn_s_sleep(1);
  }
}
// coherent (device-scope) 16B state load: two u64 atomic loads, bypass stale L1/L2,
// vmcnt-tracked by the compiler (pipelines normally). coh is wave-uniform. (r6-proven)
__device__ __forceinline__ f16x8 ldA(const f16* p, bool coh) {
  if (coh) {
    const u64* q = (const u64*)p;
    union { u64 v[2]; f16x8 h; } u;
    u.v[0] = __hip_atomic_load(q,     __ATOMIC_RELAXED, __HIP_MEMORY_SCOPE_AGENT);
    u.v[1] = __hip_atomic_load(q + 1, __ATOMIC_RELAXED, __HIP_MEMORY_SCOPE_AGENT);
    return u.h;
  }
  return *(const f16x8*)p;
}

#define MFMA16(A_, B_, C_) __builtin_amdgcn_mfma_f32_16x16x16f16(A_, B_, C_, 0, 0, 0)
// r16 zl swizzle: 64-col rows (256 B) alias all rows to the same banks; XOR bits 2-4
// of the column with (row&7) -> both the scalar writes and f32x4 reads land 2-way
// (free, m136). Preserves f32x4 alignment (bits >= 2 only) and the 0..63 col range.
#define SWZ64(r) (((r) & 7) << 2)

// Decomposition (r7/r10-proven): WG (j,s) owns 64 rows x 64 gate-cols. Wave w:
// mat = w>>2 (0: x@W, 1: h@U), K-quarter kq = w&3; Wr[32] f16x8 = 128 VGPRs,
// disjoint 32 KB A slice, depth-1 reg ring (the only non-spilling depth; r13 spilled).
// r16: SINGLE-phase reduce in a full-width zl[8][64][64] tile (128 KiB) ->
//   2 barriers/stage: writes -> BAR_A -> reads+epilogue+stores -> drain -> BAR_B.
// (writes need no entry barrier: prev stage's reads finished before its BAR_B.)
__global__ __launch_bounds__(512, 2) void k_main(const float* __restrict__ W,
                                                 const float* __restrict__ U,
                                                 const float* __restrict__ bias,
                                                 float* __restrict__ out) {
  const int j = blockIdx.x >> 6, s = blockIdx.x & 63;
  const int tid = threadIdx.x, lane = tid & 63, wv = tid >> 6;
  const int mat = wv >> 2, kq = wv & 3;
  __shared__ float zl[32768];  // [8 waves][64 rows][64 cols], swizzled, 128 KiB

  // ---- one-time weight gather f32 -> fp16 regs (r4-verified) ----
  const float* src = (mat ? U : W) + (size_t)j * (HH * 4 * HH);
  const int colb = s * 16 + (lane & 15);
  const int kb0 = kq * 256 + ((lane >> 4) << 2);
  f16x8 Wr[32];
#pragma unroll
  for (int kk = 0; kk < 16; ++kk)
#pragma unroll
    for (int cfp = 0; cfp < 2; ++cfp) {
      f16x8 v;
#pragma unroll
      for (int hf = 0; hf < 2; ++hf)
#pragma unroll
        for (int e = 0; e < 4; ++e)
          v[hf * 4 + e] = (f16)src[(size_t)(kb0 + kk * 16 + e) * 4096 + (cfp * 2 + hf) * 1024 + colb];
      Wr[kk * 2 + cfp] = v;
    }

  // ---- per-thread epilogue constants (r10-verified) ----
  const bool act = tid < 256;
  const int row = (tid & 255) >> 2;        // 0..63
  const int hl0q = (tid & 3) * 4;          // 0,4,8,12
  const int hu0 = s * 16 + hl0q;           // 4-aligned
  f32x4 brg[4];
#pragma unroll
  for (int g = 0; g < 4; ++g) brg[g] = *(const f32x4*)&bias[j * 4096 + g * 1024 + hu0];
  const int grp = (((row >> 4) * 32 + (hu0 >> 5)) * 64 +
                   ((((hu0 >> 2) & 3) << 4) | (row & 15)));
  const int e0 = ((hu0 >> 4) & 1) << 2;
  const int g64 = grp * 2 + (e0 >> 2);     // u64 index within a slot (slot = 16384 u64)
  u64* const hP = (u64*)&g_h16[j][0][0];
  u64* const cP = (u64*)&g_c16[j][0][0];
  float* const c32p = &g_c32[j][row][hu0];
  const int ktp0 = kq * 8;
  const bool coh = mat || (j > 0);  // in16 is pre-launch constant -> plain loads ok
  const unsigned* epX = (j > 0) ? &g_ep[j - 1][kq * 16 + (lane & 15)] : nullptr;
  const unsigned* epH = &g_ep[j][kq * 16 + (lane & 15)];
  const unsigned* epA = (j < 3) ? &g_ep[j + 1][lane] : nullptr;  // anti-overwrite

  for (int t = 0; t < TT; ++t) {
    // ---- per-wave dependency waits (no fences, no RMW flags; r10-proven) ----
    if (mat == 0) {
      if (j > 0) waitep(epX, (unsigned)(t + 1));       // layer below finished step t
    } else {
      if (t > 0) waitep(epH, (unsigned)t);             // own layer finished step t-1
      if (j < 3 && t >= 7) waitep(epA, (unsigned)(t - 6));  // slot reuse: ~pre-satisfied
    }
    asm volatile("" ::: "memory");  // forbid hoisting A loads above the polls

    const f16* Ab = mat ? &g_h16[j][t & 7][0]
                        : (j ? &g_c16[j - 1][(t + 1) & 7][0] : &g_in16[t][0]);
    f16x8 a[2][4];
#pragma unroll
    for (int rf = 0; rf < 4; ++rf)
      a[0][rf] = ldA(Ab + (rf * 32 + ktp0) * 512 + lane * 8, coh);

    f32x4 acc[4][4];
#pragma unroll
    for (int rf = 0; rf < 4; ++rf)
#pragma unroll
      for (int cf = 0; cf < 4; ++cf) acc[rf][cf] = (f32x4){0.f, 0.f, 0.f, 0.f};

#pragma unroll
    for (int kc = 0; kc < 8; ++kc) {
      if (kc < 7) {
#pragma unroll
        for (int rf = 0; rf < 4; ++rf)
          a[(kc + 1) & 1][rf] = ldA(Ab + (rf * 32 + ktp0 + kc + 1) * 512 + lane * 8, coh);
      }
#pragma unroll
      for (int hf = 0; hf < 2; ++hf) {
        f16x4 a4[4];
#pragma unroll
        for (int rf = 0; rf < 4; ++rf)
          a4[rf] = hf ? hi8(a[kc & 1][rf]) : lo8(a[kc & 1][rf]);
#pragma unroll
        for (int cf = 0; cf < 4; ++cf) {
          const f16x8 wreg = Wr[(kc * 2 + hf) * 2 + (cf >> 1)];
          const f16x4 b4 = (cf & 1) ? hi8(wreg) : lo8(wreg);
#pragma unroll
          for (int rf = 0; rf < 4; ++rf) acc[rf][cf] = MFMA16(a4[rf], b4, acc[rf][cf]);
        }
      }
    }

    // ---- single-phase 8-wave reduction: 2 barriers/stage (r16) ----
    // writes: no entry barrier needed (prev stage's reads done before its BAR_B)
#pragma unroll
    for (int rf = 0; rf < 4; ++rf)
#pragma unroll
      for (int cf = 0; cf < 4; ++cf)
#pragma unroll
        for (int ri = 0; ri < 4; ++ri) {
          const int rr = rf * 16 + ((lane >> 4) << 2) + ri;
          const int cc = cf * 16 + (lane & 15);
          zl[wv * 4096 + rr * 64 + (cc ^ SWZ64(rr))] = acc[rf][cf][ri];
        }
    __syncthreads();  // BAR_A: all partials visible; joins x/h waves

    if (act) {
      float gsum[4][4];  // [el 0..3][gate]
#pragma unroll
      for (int g = 0; g < 4; ++g) {
        const int swcol = (g * 16 + hl0q) ^ SWZ64(row);  // 4-aligned
        f32x4 ss = (f32x4){0.f, 0.f, 0.f, 0.f};
#pragma unroll
        for (int w = 0; w < 8; ++w) ss += *(const f32x4*)&zl[w * 4096 + row * 64 + swcol];
#pragma unroll
        for (int el = 0; el < 4; ++el) gsum[el][g] = ss[el];
      }

      // ---- gates + state update (i,f,g,o); 8B coherent publish (r10-verified) ----
      const f32x4 cp = *(const f32x4*)c32p;
      f32x4 cn, hn;
#pragma unroll
      for (int el = 0; el < 4; ++el) {
        const float zi = gsum[el][0] + brg[0][el];
        const float zf = gsum[el][1] + brg[1][el];
        const float zg = gsum[el][2] + brg[2][el];
        const float zo = gsum[el][3] + brg[3][el];
        cn[el] = sigf(zf) * cp[el] + sigf(zi) * tanh_(zg);
        hn[el] = sigf(zo) * tanh_(cn[el]);
      }
      *(f32x4*)c32p = cn;
      union { f16 h[4]; u64 u; } ph, pc;
#pragma unroll
      for (int el = 0; el < 4; ++el) { ph.h[el] = (f16)hn[el]; pc.h[el] = (f16)cn[el]; }
      const int slot = (t + 1) & 7;
      __hip_atomic_store(hP + (size_t)slot * 16384 + g64, ph.u,
                         __ATOMIC_RELAXED, __HIP_MEMORY_SCOPE_AGENT);
      if (j < 3)
        __hip_atomic_store(cP + (size_t)slot * 16384 + g64, pc.u,
                           __ATOMIC_RELAXED, __HIP_MEMORY_SCOPE_AGENT);
      if (j == 3 && t == TT - 1) *(f32x4*)&out[(row << 10) + hu0] = cn;
    }

    // ---- publish: drain device-scope stores, barrier, single epoch STORE ----
    asm volatile("s_waitcnt vmcnt(0)" ::: "memory");
    __syncthreads();  // BAR_B: all stores drained; zl reads done
    if (tid == 0)
      __hip_atomic_store(&g_ep[j][s], (unsigned)(t + 1),
                         __ATOMIC_RELAXED, __HIP_MEMORY_SCOPE_AGENT);
  }
}

extern "C" void kernel_launch(void* const* d_in, const int* in_sizes, int n_in,
                              void* d_out, int out_size, void* d_ws, size_t ws_size,
                              hipStream_t stream) {
  const float* inp  = (const float*)d_in[0];
  const float* W    = (const float*)d_in[1];
  const float* U    = (const float*)d_in[2];
  const float* bias = (const float*)d_in[3];
  float* out = (float*)d_out;
  k_init<<<256, 256, 0, stream>>>();
  k_pack_in<<<4096, 512, 0, stream>>>(inp);
  k_main<<<NWG, 512, 0, stream>>>(W, U, bias, out);
}

// Round 17
// 2066.280 us; speedup vs baseline: 1.6751x; 1.6751x over previous
//
#include <hip/hip_runtime.h>

#define TT 128
#define BB 64
#define HH 1024
#define LL 4
#define NWG 256

typedef _Float16 f16;
typedef __attribute__((ext_vector_type(4))) _Float16 f16x4;
typedef __attribute__((ext_vector_type(8))) _Float16 f16x8;
typedef __attribute__((ext_vector_type(4))) float f32x4;
typedef unsigned long long u64;

// ---------------- persistent device buffers ----------------
// Fragment layout for a [64 rows x 1024 k] fp16 tensor (HW-verified r1/r4/r6/r7):
//   flat = ((rg*32 + ktp)*64 + lane)*8 + e
//   rg = row>>4, ktp = k>>5, lane = ((k>>2)&3)<<4 | (row&15), e = ((k>>4)&1)<<2 | (k&3)
__device__ __align__(16) f16 g_in16[TT][65536];        // inputs, frag layout per t
// 8-deep rotating state slots (t&7): slot (t+1)&7 holds post-step-t state.
// Producers publish with device-scope atomic stores; consumers read with
// device-scope atomic loads (bypass stale L1/L2). NO cache-wide fences (r10/r15).
__device__ __align__(16) f16 g_c16[LL][8][65536];      // cell state (feeds next layer)
__device__ __align__(16) f16 g_h16[LL][8][65536];      // hidden state (U-matmul input)
__device__ __align__(16) float g_c32[LL][BB][HH];      // cell state master f32 (WG-private)
// per-producer epoch: g_ep[j][s] = t+1 after WG (j,s) finished step t (atomic STORE).
__device__ unsigned g_ep[LL][64];

// ---------------- init: zero h slot 0 + epochs + c32 ----------------
__global__ void k_init() {
  unsigned tid = blockIdx.x * blockDim.x + threadIdx.x;
  unsigned n = gridDim.x * blockDim.x;
  float* c32 = &g_c32[0][0][0];
  for (unsigned i = tid; i < LL * BB * HH; i += n) c32[i] = 0.f;
  for (unsigned i = tid; i < LL * 32768; i += n) {
    int jj = i >> 15, q = i & 32767;
    ((unsigned*)&g_h16[jj][0][0])[q] = 0u;   // h(0) = 0 in slot 0
  }
  unsigned* pe = &g_ep[0][0];
  for (unsigned i = tid; i < LL * 64; i += n) pe[i] = 0u;
}

// ---------------- pack inputs f32 -> fp16 fragment layout (verified) ----------------
__global__ void k_pack_in(const float* __restrict__ inp) {
  int tid = blockIdx.x * blockDim.x + threadIdx.x;
  int t = tid >> 14, q = tid & 16383;
  int row = q >> 8, hu = (q & 255) << 2;
  const float4 x = *(const float4*)(inp + ((size_t)t << 16) + (row << 10) + hu);
  int rg = row >> 4, ktp = hu >> 5;
  int ln = (((hu >> 2) & 3) << 4) | (row & 15);
  int e0 = ((hu >> 4) & 1) << 2;
  f16x4 v = {(f16)x.x, (f16)x.y, (f16)x.z, (f16)x.w};
  *(f16x4*)&g_in16[t][(((rg * 32 + ktp) * 64 + ln) << 3) + e0] = v;
}

// ---------------- helpers ----------------
__device__ __forceinline__ float sigf(float x) { return 1.f / (1.f + __expf(-x)); }
__device__ __forceinline__ float tanh_(float x) {
  float q = __expf(-2.f * fabsf(x));
  return copysignf((1.f - q) / (1.f + q), x);
}
__device__ __forceinline__ f16x4 lo8(f16x8 v) { return __builtin_shufflevector(v, v, 0, 1, 2, 3); }
__device__ __forceinline__ f16x4 hi8(f16x8 v) { return __builtin_shufflevector(v, v, 4, 5, 6, 7); }
// lane-parallel wait: lane l polls its own producer-epoch slot; exit when all >= target
__device__ __forceinline__ void waitep(const unsigned* ep, unsigned target) {
  for (;;) {
    unsigned e = __hip_atomic_load(ep, __ATOMIC_RELAXED, __HIP_MEMORY_SCOPE_AGENT);
    if (__all((int)(e >= target))) break;
    __builtin_amdgcn_s_sleep(1);
  }
}
// r17: fused dual wait — poll both conditions in one loop (cost = max, not sum)
__device__ __forceinline__ void waitep2(const unsigned* p1, unsigned n1,
                                        const unsigned* p2, unsigned n2) {
  for (;;) {
    unsigned e1 = __hip_atomic_load(p1, __ATOMIC_RELAXED, __HIP_MEMORY_SCOPE_AGENT);
    unsigned e2 = __hip_atomic_load(p2, __ATOMIC_RELAXED, __HIP_MEMORY_SCOPE_AGENT);
    if (__all((int)((e1 >= n1) & (e2 >= n2)))) break;
    __builtin_amdgcn_s_sleep(1);
  }
}
// coherent (device-scope) 16B state load: two u64 atomic loads, bypass stale L1/L2,
// vmcnt-tracked by the compiler (pipelines normally). coh is wave-uniform. (r6-proven)
__device__ __forceinline__ f16x8 ldA(const f16* p, bool coh) {
  if (coh) {
    const u64* q = (const u64*)p;
    union { u64 v[2]; f16x8 h; } u;
    u.v[0] = __hip_atomic_load(q,     __ATOMIC_RELAXED, __HIP_MEMORY_SCOPE_AGENT);
    u.v[1] = __hip_atomic_load(q + 1, __ATOMIC_RELAXED, __HIP_MEMORY_SCOPE_AGENT);
    return u.h;
  }
  return *(const f16x8*)p;
}

#define MFMA16(A_, B_, C_) __builtin_amdgcn_mfma_f32_16x16x16f16(A_, B_, C_, 0, 0, 0)
#define SWZ(r) ((((r) & 4) << 2) ^ (((r) & 3) << 3))

// Decomposition (r7/r10-proven): WG (j,s) owns 64 rows x 64 gate-cols. Wave w:
// mat = w>>2 (0: x@W, 1: h@U), K-quarter kq = w&3; Wr[32] f16x8 = 128 VGPRs,
// disjoint 32 KB A slice, depth-1 reg ring (the only non-spilling depth; r13 spilled).
// r15 reduce (proven best): ping-pong zl buffers (128 KiB) -> 3 barriers/stage:
//   wA -> BAR -> {rA || wB} -> BAR -> rB+epilogue -> drain+BAR -> epoch store.
// r17 deltas: (1) fused h-wave poll (epH & epA in ONE loop — epA was a serialized
// pre-satisfied MALL read on the h critical path); (2) s_setprio(1) around GEMM
// (T5: waves here have genuine phase diversity — h-GEMM runs while x-waves poll).
__global__ __launch_bounds__(512, 2) void k_main(const float* __restrict__ W,
                                                 const float* __restrict__ U,
                                                 const float* __restrict__ bias,
                                                 float* __restrict__ out) {
  const int j = blockIdx.x >> 6, s = blockIdx.x & 63;
  const int tid = threadIdx.x, lane = tid & 63, wv = tid >> 6;
  const int mat = wv >> 2, kq = wv & 3;
  __shared__ float zl[2][16384];  // ping-pong: [phase][wave][row][32 colhalf], 128 KiB

  // ---- one-time weight gather f32 -> fp16 regs (r4-verified) ----
  const float* src = (mat ? U : W) + (size_t)j * (HH * 4 * HH);
  const int colb = s * 16 + (lane & 15);
  const int kb0 = kq * 256 + ((lane >> 4) << 2);
  f16x8 Wr[32];
#pragma unroll
  for (int kk = 0; kk < 16; ++kk)
#pragma unroll
    for (int cfp = 0; cfp < 2; ++cfp) {
      f16x8 v;
#pragma unroll
      for (int hf = 0; hf < 2; ++hf)
#pragma unroll
        for (int e = 0; e < 4; ++e)
          v[hf * 4 + e] = (f16)src[(size_t)(kb0 + kk * 16 + e) * 4096 + (cfp * 2 + hf) * 1024 + colb];
      Wr[kk * 2 + cfp] = v;
    }

  // ---- per-thread epilogue constants (r10-verified) ----
  const bool act = tid < 256;
  const int row = (tid & 255) >> 2;        // 0..63
  const int hl0q = (tid & 3) * 4;          // 0,4,8,12
  const int hu0 = s * 16 + hl0q;           // 4-aligned
  f32x4 brg[4];
#pragma unroll
  for (int g = 0; g < 4; ++g) brg[g] = *(const f32x4*)&bias[j * 4096 + g * 1024 + hu0];
  const int grp = (((row >> 4) * 32 + (hu0 >> 5)) * 64 +
                   ((((hu0 >> 2) & 3) << 4) | (row & 15)));
  const int e0 = ((hu0 >> 4) & 1) << 2;
  const int g64 = grp * 2 + (e0 >> 2);     // u64 index within a slot (slot = 16384 u64)
  u64* const hP = (u64*)&g_h16[j][0][0];
  u64* const cP = (u64*)&g_c16[j][0][0];
  float* const c32p = &g_c32[j][row][hu0];
  const int ktp0 = kq * 8;
  const bool coh = mat || (j > 0);  // in16 is pre-launch constant -> plain loads ok
  const unsigned* epX = (j > 0) ? &g_ep[j - 1][kq * 16 + (lane & 15)] : nullptr;
  const unsigned* epH = &g_ep[j][kq * 16 + (lane & 15)];
  const unsigned* epA = (j < 3) ? &g_ep[j + 1][lane] : nullptr;  // anti-overwrite

  for (int t = 0; t < TT; ++t) {
    // ---- per-wave dependency waits (no fences, no RMW flags; r10-proven) ----
    if (mat == 0) {
      if (j > 0) waitep(epX, (unsigned)(t + 1));       // layer below finished step t
    } else {
      const bool na = (j < 3 && t >= 7);
      if (t > 0) {
        if (na) waitep2(epH, (unsigned)t, epA, (unsigned)(t - 6));  // fused (r17)
        else    waitep(epH, (unsigned)t);              // own layer finished step t-1
      }
    }
    asm volatile("" ::: "memory");  // forbid hoisting A loads above the polls

    const f16* Ab = mat ? &g_h16[j][t & 7][0]
                        : (j ? &g_c16[j - 1][(t + 1) & 7][0] : &g_in16[t][0]);

    __builtin_amdgcn_s_setprio(1);  // T5: favor GEMM-phase waves over pollers
    f16x8 a[2][4];
#pragma unroll
    for (int rf = 0; rf < 4; ++rf)
      a[0][rf] = ldA(Ab + (rf * 32 + ktp0) * 512 + lane * 8, coh);

    f32x4 acc[4][4];
#pragma unroll
    for (int rf = 0; rf < 4; ++rf)
#pragma unroll
      for (int cf = 0; cf < 4; ++cf) acc[rf][cf] = (f32x4){0.f, 0.f, 0.f, 0.f};

#pragma unroll
    for (int kc = 0; kc < 8; ++kc) {
      if (kc < 7) {
#pragma unroll
        for (int rf = 0; rf < 4; ++rf)
          a[(kc + 1) & 1][rf] = ldA(Ab + (rf * 32 + ktp0 + kc + 1) * 512 + lane * 8, coh);
      }
#pragma unroll
      for (int hf = 0; hf < 2; ++hf) {
        f16x4 a4[4];
#pragma unroll
        for (int rf = 0; rf < 4; ++rf)
          a4[rf] = hf ? hi8(a[kc & 1][rf]) : lo8(a[kc & 1][rf]);
#pragma unroll
        for (int cf = 0; cf < 4; ++cf) {
          const f16x8 wreg = Wr[(kc * 2 + hf) * 2 + (cf >> 1)];
          const f16x4 b4 = (cf & 1) ? hi8(wreg) : lo8(wreg);
#pragma unroll
          for (int rf = 0; rf < 4; ++rf) acc[rf][cf] = MFMA16(a4[rf], b4, acc[rf][cf]);
        }
      }
    }
    __builtin_amdgcn_s_setprio(0);

    // ---- ping-pong 8-wave reduction: 3 barriers total (r15-proven) ----
    float gsum[4][4];  // [el 0..3][gate]
    // phase A writes (gates 0,1) -> zl[0]; no entry barrier needed (see header note)
#pragma unroll
    for (int rf = 0; rf < 4; ++rf)
#pragma unroll
      for (int ch = 0; ch < 2; ++ch)
#pragma unroll
        for (int ri = 0; ri < 4; ++ri) {
          const int rr = rf * 16 + ((lane >> 4) << 2) + ri;
          const int c2 = ch * 16 + (lane & 15);
          zl[0][wv * 2048 + rr * 32 + (c2 ^ SWZ(rr))] = acc[rf][ch][ri];
        }
    __syncthreads();  // BAR1: phase-A visible; joins x/h waves
    // phase B writes (gates 2,3) -> zl[1], overlapping phase-A reads
#pragma unroll
    for (int rf = 0; rf < 4; ++rf)
#pragma unroll
      for (int ch = 0; ch < 2; ++ch)
#pragma unroll
        for (int ri = 0; ri < 4; ++ri) {
          const int rr = rf * 16 + ((lane >> 4) << 2) + ri;
          const int c2 = ch * 16 + (lane & 15);
          zl[1][wv * 2048 + rr * 32 + (c2 ^ SWZ(rr))] = acc[rf][2 + ch][ri];
        }
    if (act) {
#pragma unroll
      for (int ch = 0; ch < 2; ++ch) {
        const int swcol = (ch * 16 + hl0q) ^ SWZ(row);  // 4-aligned
        f32x4 ss = (f32x4){0.f, 0.f, 0.f, 0.f};
#pragma unroll
        for (int w = 0; w < 8; ++w) ss += *(const f32x4*)&zl[0][w * 2048 + row * 32 + swcol];
#pragma unroll
        for (int el = 0; el < 4; ++el) gsum[el][ch] = ss[el];
      }
    }
    __syncthreads();  // BAR2: phase-B visible; phase-A reads done
    if (act) {
#pragma unroll
      for (int ch = 0; ch < 2; ++ch) {
        const int swcol = (ch * 16 + hl0q) ^ SWZ(row);
        f32x4 ss = (f32x4){0.f, 0.f, 0.f, 0.f};
#pragma unroll
        for (int w = 0; w < 8; ++w) ss += *(const f32x4*)&zl[1][w * 2048 + row * 32 + swcol];
#pragma unroll
        for (int el = 0; el < 4; ++el) gsum[el][2 + ch] = ss[el];
      }

      // ---- gates + state update (i,f,g,o); 8B coherent publish (r10-verified) ----
      const f32x4 cp = *(const f32x4*)c32p;
      f32x4 cn, hn;
#pragma unroll
      for (int el = 0; el < 4; ++el) {
        const float zi = gsum[el][0] + brg[0][el];
        const float zf = gsum[el][1] + brg[1][el];
        const float zg = gsum[el][2] + brg[2][el];
        const float zo = gsum[el][3] + brg[3][el];
        cn[el] = sigf(zf) * cp[el] + sigf(zi) * tanh_(zg);
        hn[el] = sigf(zo) * tanh_(cn[el]);
      }
      *(f32x4*)c32p = cn;
      union { f16 h[4]; u64 u; } ph, pc;
#pragma unroll
      for (int el = 0; el < 4; ++el) { ph.h[el] = (f16)hn[el]; pc.h[el] = (f16)cn[el]; }
      const int slot = (t + 1) & 7;
      __hip_atomic_store(hP + (size_t)slot * 16384 + g64, ph.u,
                         __ATOMIC_RELAXED, __HIP_MEMORY_SCOPE_AGENT);
      if (j < 3)
        __hip_atomic_store(cP + (size_t)slot * 16384 + g64, pc.u,
                           __ATOMIC_RELAXED, __HIP_MEMORY_SCOPE_AGENT);
      if (j == 3 && t == TT - 1) *(f32x4*)&out[(row << 10) + hu0] = cn;
    }

    // ---- publish: drain device-scope stores, barrier, single epoch STORE ----
    asm volatile("s_waitcnt vmcnt(0)" ::: "memory");
    __syncthreads();  // BAR3: all stores drained; zl[1] reads done
    if (tid == 0)
      __hip_atomic_store(&g_ep[j][s], (unsigned)(t + 1),
                         __ATOMIC_RELAXED, __HIP_MEMORY_SCOPE_AGENT);
  }
}

extern "C" void kernel_launch(void* const* d_in, const int* in_sizes, int n_in,
                              void* d_out, int out_size, void* d_ws, size_t ws_size,
                              hipStream_t stream) {
  const float* inp  = (const float*)d_in[0];
  const float* W    = (const float*)d_in[1];
  const float* U    = (const float*)d_in[2];
  const float* bias = (const float*)d_in[3];
  float* out = (float*)d_out;
  k_init<<<256, 256, 0, stream>>>();
  k_pack_in<<<4096, 512, 0, stream>>>(inp);
  k_main<<<NWG, 512, 0, stream>>>(W, U, bias, out);
}

// Round 18
// 2021.338 us; speedup vs baseline: 1.7123x; 1.0222x over previous
//
#include <hip/hip_runtime.h>

#define TT 128
#define BB 64
#define HH 1024
#define LL 4
#define NWG 256

typedef _Float16 f16;
typedef __attribute__((ext_vector_type(4))) _Float16 f16x4;
typedef __attribute__((ext_vector_type(8))) _Float16 f16x8;
typedef __attribute__((ext_vector_type(4))) float f32x4;
typedef unsigned long long u64;

// ---------------- persistent device buffers ----------------
// Fragment layout for a [64 rows x 1024 k] fp16 tensor (HW-verified r1/r4/r6/r7):
//   flat = ((rg*32 + ktp)*64 + lane)*8 + e
//   rg = row>>4, ktp = k>>5, lane = ((k>>2)&3)<<4 | (row&15), e = ((k>>4)&1)<<2 | (k&3)
__device__ __align__(16) f16 g_in16[TT][65536];        // inputs, frag layout per t
// 8-deep rotating state slots (t&7): slot (t+1)&7 holds post-step-t state.
// Producers publish with device-scope atomic stores; consumers read with
// device-scope atomic loads (bypass stale L1/L2). NO cache-wide fences (r10-proven).
// 8 slots push the anti-overwrite wait target to t-6, satisfied ~5 ticks in
// advance -> the 64-wide poll exits on first read.
__device__ __align__(16) f16 g_c16[LL][8][65536];      // cell state (feeds next layer)
__device__ __align__(16) f16 g_h16[LL][8][65536];      // hidden state (U-matmul input)
__device__ __align__(16) float g_c32[LL][BB][HH];      // cell state master f32 (WG-private)
// per-producer epoch: g_ep[j][s] = t+1 after WG (j,s) finished step t (atomic STORE).
__device__ unsigned g_ep[LL][64];

// ---------------- init: zero h slot 0 + epochs + c32 ----------------
__global__ void k_init() {
  unsigned tid = blockIdx.x * blockDim.x + threadIdx.x;
  unsigned n = gridDim.x * blockDim.x;
  float* c32 = &g_c32[0][0][0];
  for (unsigned i = tid; i < LL * BB * HH; i += n) c32[i] = 0.f;
  for (unsigned i = tid; i < LL * 32768; i += n) {
    int jj = i >> 15, q = i & 32767;
    ((unsigned*)&g_h16[jj][0][0])[q] = 0u;   // h(0) = 0 in slot 0
  }
  unsigned* pe = &g_ep[0][0];
  for (unsigned i = tid; i < LL * 64; i += n) pe[i] = 0u;
}

// ---------------- pack inputs f32 -> fp16 fragment layout (verified) ----------------
__global__ void k_pack_in(const float* __restrict__ inp) {
  int tid = blockIdx.x * blockDim.x + threadIdx.x;
  int t = tid >> 14, q = tid & 16383;
  int row = q >> 8, hu = (q & 255) << 2;
  const float4 x = *(const float4*)(inp + ((size_t)t << 16) + (row << 10) + hu);
  int rg = row >> 4, ktp = hu >> 5;
  int ln = (((hu >> 2) & 3) << 4) | (row & 15);
  int e0 = ((hu >> 4) & 1) << 2;
  f16x4 v = {(f16)x.x, (f16)x.y, (f16)x.z, (f16)x.w};
  *(f16x4*)&g_in16[t][(((rg * 32 + ktp) * 64 + ln) << 3) + e0] = v;
}

// ---------------- helpers ----------------
__device__ __forceinline__ float sigf(float x) { return 1.f / (1.f + __expf(-x)); }
__device__ __forceinline__ float tanh_(float x) {
  float q = __expf(-2.f * fabsf(x));
  return copysignf((1.f - q) / (1.f + q), x);
}
__device__ __forceinline__ f16x4 lo8(f16x8 v) { return __builtin_shufflevector(v, v, 0, 1, 2, 3); }
__device__ __forceinline__ f16x4 hi8(f16x8 v) { return __builtin_shufflevector(v, v, 4, 5, 6, 7); }
// lane-parallel wait: lane l polls its own producer-epoch slot; exit when all >= target
__device__ __forceinline__ void waitep(const unsigned* ep, unsigned target) {
  for (;;) {
    unsigned e = __hip_atomic_load(ep, __ATOMIC_RELAXED, __HIP_MEMORY_SCOPE_AGENT);
    if (__all((int)(e >= target))) break;
    __builtin_amdgcn_s_sleep(1);
  }
}
// coherent (device-scope) 16B state load: two u64 atomic loads, bypass stale L1/L2,
// vmcnt-tracked by the compiler (pipelines normally). coh is wave-uniform. (r6-proven)
__device__ __forceinline__ f16x8 ldA(const f16* p, bool coh) {
  if (coh) {
    const u64* q = (const u64*)p;
    union { u64 v[2]; f16x8 h; } u;
    u.v[0] = __hip_atomic_load(q,     __ATOMIC_RELAXED, __HIP_MEMORY_SCOPE_AGENT);
    u.v[1] = __hip_atomic_load(q + 1, __ATOMIC_RELAXED, __HIP_MEMORY_SCOPE_AGENT);
    return u.h;
  }
  return *(const f16x8*)p;
}

#define MFMA16(A_, B_, C_) __builtin_amdgcn_mfma_f32_16x16x16f16(A_, B_, C_, 0, 0, 0)
#define SWZ(r) ((((r) & 4) << 2) ^ (((r) & 3) << 3))

// Decomposition (r7/r10-proven): WG (j,s) owns 64 rows x 64 gate-cols. Wave w:
// mat = w>>2 (0: x@W, 1: h@U), K-quarter kq = w&3; Wr[32] f16x8 = 128 VGPRs,
// disjoint 32 KB A slice, depth-1 reg ring (the only non-spilling depth; r13 spilled).
// r15 reduce (proven best): ping-pong zl buffers (128 KiB LDS) -> 3 barriers/stage:
//   wA -> BAR -> {rA || wB} -> BAR -> rB+epilogue -> drain+BAR -> epoch store.
// (wA needs no entry barrier: prev stage's rA finished before its publish barrier.)
// r18: byte-exact r15 revert — r17's setprio (m190: negative on lockstep GEMM) and
// fused poll are removed for clean attribution of the 2015->2066 regression.
__global__ __launch_bounds__(512, 2) void k_main(const float* __restrict__ W,
                                                 const float* __restrict__ U,
                                                 const float* __restrict__ bias,
                                                 float* __restrict__ out) {
  const int j = blockIdx.x >> 6, s = blockIdx.x & 63;
  const int tid = threadIdx.x, lane = tid & 63, wv = tid >> 6;
  const int mat = wv >> 2, kq = wv & 3;
  __shared__ float zl[2][16384];  // ping-pong: [phase][wave][row][32 colhalf], 128 KiB

  // ---- one-time weight gather f32 -> fp16 regs (r4-verified) ----
  const float* src = (mat ? U : W) + (size_t)j * (HH * 4 * HH);
  const int colb = s * 16 + (lane & 15);
  const int kb0 = kq * 256 + ((lane >> 4) << 2);
  f16x8 Wr[32];
#pragma unroll
  for (int kk = 0; kk < 16; ++kk)
#pragma unroll
    for (int cfp = 0; cfp < 2; ++cfp) {
      f16x8 v;
#pragma unroll
      for (int hf = 0; hf < 2; ++hf)
#pragma unroll
        for (int e = 0; e < 4; ++e)
          v[hf * 4 + e] = (f16)src[(size_t)(kb0 + kk * 16 + e) * 4096 + (cfp * 2 + hf) * 1024 + colb];
      Wr[kk * 2 + cfp] = v;
    }

  // ---- per-thread epilogue constants (r10-verified) ----
  const bool act = tid < 256;
  const int row = (tid & 255) >> 2;        // 0..63
  const int hl0q = (tid & 3) * 4;          // 0,4,8,12
  const int hu0 = s * 16 + hl0q;           // 4-aligned
  f32x4 brg[4];
#pragma unroll
  for (int g = 0; g < 4; ++g) brg[g] = *(const f32x4*)&bias[j * 4096 + g * 1024 + hu0];
  const int grp = (((row >> 4) * 32 + (hu0 >> 5)) * 64 +
                   ((((hu0 >> 2) & 3) << 4) | (row & 15)));
  const int e0 = ((hu0 >> 4) & 1) << 2;
  const int g64 = grp * 2 + (e0 >> 2);     // u64 index within a slot (slot = 16384 u64)
  u64* const hP = (u64*)&g_h16[j][0][0];
  u64* const cP = (u64*)&g_c16[j][0][0];
  float* const c32p = &g_c32[j][row][hu0];
  const int ktp0 = kq * 8;
  const bool coh = mat || (j > 0);  // in16 is pre-launch constant -> plain loads ok
  const unsigned* epX = (j > 0) ? &g_ep[j - 1][kq * 16 + (lane & 15)] : nullptr;
  const unsigned* epH = &g_ep[j][kq * 16 + (lane & 15)];
  const unsigned* epA = (j < 3) ? &g_ep[j + 1][lane] : nullptr;  // anti-overwrite

  for (int t = 0; t < TT; ++t) {
    // ---- per-wave dependency waits (no fences, no RMW flags; r10-proven) ----
    if (mat == 0) {
      if (j > 0) waitep(epX, (unsigned)(t + 1));       // layer below finished step t
    } else {
      if (t > 0) waitep(epH, (unsigned)t);             // own layer finished step t-1
      if (j < 3 && t >= 7) waitep(epA, (unsigned)(t - 6));  // slot reuse: ~pre-satisfied
    }
    asm volatile("" ::: "memory");  // forbid hoisting A loads above the polls

    const f16* Ab = mat ? &g_h16[j][t & 7][0]
                        : (j ? &g_c16[j - 1][(t + 1) & 7][0] : &g_in16[t][0]);
    f16x8 a[2][4];
#pragma unroll
    for (int rf = 0; rf < 4; ++rf)
      a[0][rf] = ldA(Ab + (rf * 32 + ktp0) * 512 + lane * 8, coh);

    f32x4 acc[4][4];
#pragma unroll
    for (int rf = 0; rf < 4; ++rf)
#pragma unroll
      for (int cf = 0; cf < 4; ++cf) acc[rf][cf] = (f32x4){0.f, 0.f, 0.f, 0.f};

#pragma unroll
    for (int kc = 0; kc < 8; ++kc) {
      if (kc < 7) {
#pragma unroll
        for (int rf = 0; rf < 4; ++rf)
          a[(kc + 1) & 1][rf] = ldA(Ab + (rf * 32 + ktp0 + kc + 1) * 512 + lane * 8, coh);
      }
#pragma unroll
      for (int hf = 0; hf < 2; ++hf) {
        f16x4 a4[4];
#pragma unroll
        for (int rf = 0; rf < 4; ++rf)
          a4[rf] = hf ? hi8(a[kc & 1][rf]) : lo8(a[kc & 1][rf]);
#pragma unroll
        for (int cf = 0; cf < 4; ++cf) {
          const f16x8 wreg = Wr[(kc * 2 + hf) * 2 + (cf >> 1)];
          const f16x4 b4 = (cf & 1) ? hi8(wreg) : lo8(wreg);
#pragma unroll
          for (int rf = 0; rf < 4; ++rf) acc[rf][cf] = MFMA16(a4[rf], b4, acc[rf][cf]);
        }
      }
    }

    // ---- ping-pong 8-wave reduction: 3 barriers total (r15-proven) ----
    float gsum[4][4];  // [el 0..3][gate]
    // phase A writes (gates 0,1) -> zl[0]; no entry barrier needed (see header note)
#pragma unroll
    for (int rf = 0; rf < 4; ++rf)
#pragma unroll
      for (int ch = 0; ch < 2; ++ch)
#pragma unroll
        for (int ri = 0; ri < 4; ++ri) {
          const int rr = rf * 16 + ((lane >> 4) << 2) + ri;
          const int c2 = ch * 16 + (lane & 15);
          zl[0][wv * 2048 + rr * 32 + (c2 ^ SWZ(rr))] = acc[rf][ch][ri];
        }
    __syncthreads();  // BAR1: phase-A visible; joins x/h waves
    // phase B writes (gates 2,3) -> zl[1], overlapping phase-A reads
#pragma unroll
    for (int rf = 0; rf < 4; ++rf)
#pragma unroll
      for (int ch = 0; ch < 2; ++ch)
#pragma unroll
        for (int ri = 0; ri < 4; ++ri) {
          const int rr = rf * 16 + ((lane >> 4) << 2) + ri;
          const int c2 = ch * 16 + (lane & 15);
          zl[1][wv * 2048 + rr * 32 + (c2 ^ SWZ(rr))] = acc[rf][2 + ch][ri];
        }
    if (act) {
#pragma unroll
      for (int ch = 0; ch < 2; ++ch) {
        const int swcol = (ch * 16 + hl0q) ^ SWZ(row);  // 4-aligned
        f32x4 ss = (f32x4){0.f, 0.f, 0.f, 0.f};
#pragma unroll
        for (int w = 0; w < 8; ++w) ss += *(const f32x4*)&zl[0][w * 2048 + row * 32 + swcol];
#pragma unroll
        for (int el = 0; el < 4; ++el) gsum[el][ch] = ss[el];
      }
    }
    __syncthreads();  // BAR2: phase-B visible; phase-A reads done
    if (act) {
#pragma unroll
      for (int ch = 0; ch < 2; ++ch) {
        const int swcol = (ch * 16 + hl0q) ^ SWZ(row);
        f32x4 ss = (f32x4){0.f, 0.f, 0.f, 0.f};
#pragma unroll
        for (int w = 0; w < 8; ++w) ss += *(const f32x4*)&zl[1][w * 2048 + row * 32 + swcol];
#pragma unroll
        for (int el = 0; el < 4; ++el) gsum[el][2 + ch] = ss[el];
      }

      // ---- gates + state update (i,f,g,o); 8B coherent publish (r10-verified) ----
      const f32x4 cp = *(const f32x4*)c32p;
      f32x4 cn, hn;
#pragma unroll
      for (int el = 0; el < 4; ++el) {
        const float zi = gsum[el][0] + brg[0][el];
        const float zf = gsum[el][1] + brg[1][el];
        const float zg = gsum[el][2] + brg[2][el];
        const float zo = gsum[el][3] + brg[3][el];
        cn[el] = sigf(zf) * cp[el] + sigf(zi) * tanh_(zg);
        hn[el] = sigf(zo) * tanh_(cn[el]);
      }
      *(f32x4*)c32p = cn;
      union { f16 h[4]; u64 u; } ph, pc;
#pragma unroll
      for (int el = 0; el < 4; ++el) { ph.h[el] = (f16)hn[el]; pc.h[el] = (f16)cn[el]; }
      const int slot = (t + 1) & 7;
      __hip_atomic_store(hP + (size_t)slot * 16384 + g64, ph.u,
                         __ATOMIC_RELAXED, __HIP_MEMORY_SCOPE_AGENT);
      if (j < 3)
        __hip_atomic_store(cP + (size_t)slot * 16384 + g64, pc.u,
                           __ATOMIC_RELAXED, __HIP_MEMORY_SCOPE_AGENT);
      if (j == 3 && t == TT - 1) *(f32x4*)&out[(row << 10) + hu0] = cn;
    }

    // ---- publish: drain device-scope stores, barrier, single epoch STORE ----
    asm volatile("s_waitcnt vmcnt(0)" ::: "memory");
    __syncthreads();  // BAR3: all stores drained; zl[1] reads done
    if (tid == 0)
      __hip_atomic_store(&g_ep[j][s], (unsigned)(t + 1),
                         __ATOMIC_RELAXED, __HIP_MEMORY_SCOPE_AGENT);
  }
}

extern "C" void kernel_launch(void* const* d_in, const int* in_sizes, int n_in,
                              void* d_out, int out_size, void* d_ws, size_t ws_size,
                              hipStream_t stream) {
  const float* inp  = (const float*)d_in[0];
  const float* W    = (const float*)d_in[1];
  const float* U    = (const float*)d_in[2];
  const float* bias = (const float*)d_in[3];
  float* out = (float*)d_out;
  k_init<<<256, 256, 0, stream>>>();
  k_pack_in<<<4096, 512, 0, stream>>>(inp);
  k_main<<<NWG, 512, 0, stream>>>(W, U, bias, out);
}